// Round 5
// baseline (419.306 us; speedup 1.0000x reference)
//
#include <hip/hip_runtime.h>
#include <math.h>
#include <stdint.h>

// ScaleAdaptiveRouter on MI355X (gfx950) — Round 5
// T=16384, H=2048, E=64, K=2112, top-2.
//
// R4 post-mortem: W reads scalarized (SGPR_Count maxed at 112) ->
// s_load + lgkmcnt(0) per j serialized against ds_read; VALUBusy 18%.
// R5: same lane=token / wave=8-expert mapping, but W fed through a deep
// VMEM pipeline instead of the scalar pipe:
//   * opaque VGPR zero (inline asm) added to W2 address -> compiler must
//     emit global_load_dwordx4 (vmcnt, broadcast), never s_load.
//   * W double-buffered in VGPRs at 2-j granularity (64 VGPRs/buf):
//     issue group g+1, compute group g -> ~256 issue-cycles of cover.
//   * __launch_bounds__(512,2): we run 2 waves/SIMD, unlock 256 VGPRs.
//   * x path unchanged from R4 (swizzled LDS, zero-conflict b128).

#define H_DIM 2048
#define K_TOTAL 2112
#define E_DIM 64
#define SE_DIM 64
#define BK 64
#define NKB (H_DIM / BK)        // 32 x-tiles
#define TPB 64                  // tokens per block (lane = token)
#define NBLOCKS (16384 / TPB)   // 256
#define NK4 (K_TOTAL / 4)       // 528
#define EPW 8                   // experts per wave
#define NGROUPS (H_DIM / 8)     // 256 W-groups of 2 k4-rows each

// ---- prep: W2[k4*64 + e] = float4(W[e][4k4 .. 4k4+3]) ----
__global__ void pack_w_kernel(const float* __restrict__ W, float4* __restrict__ W2) {
    int tid = blockIdx.x * 256 + threadIdx.x;      // 0 .. 33791
    int e  = tid / NK4;
    int k4 = tid - e * NK4;
    float4 v = *(const float4*)(W + (size_t)e * K_TOTAL + 4 * k4);
    W2[(size_t)k4 * E_DIM + e] = v;
}

// load W group g (k4 rows 2g, 2g+1; this wave's 8 experts) into dst[16]
#define WLOAD(dst, g) do {                                        \
    const float4* _w = wp + (size_t)(g) * (2 * E_DIM);            \
    _Pragma("unroll")                                             \
    for (int _i = 0; _i < 8; ++_i) {                              \
        dst[_i]     = _w[_i];          /* row 2g   */             \
        dst[8 + _i] = _w[E_DIM + _i];  /* row 2g+1 */             \
    }                                                             \
} while (0)

__launch_bounds__(512, 2)
__global__ void ScaleAdaptiveRouter_kernel(const float* __restrict__ x,
                                           const float* __restrict__ se,
                                           const float4* __restrict__ W2,
                                           const float* __restrict__ noise,
                                           const int* __restrict__ sidx,
                                           float* __restrict__ out) {
    __shared__ __align__(16) float xs[2][TPB * BK];   // 2 x 16 KB x-tiles
    __shared__ float4 cand[8 * TPB];                  // 8 KB top-2 candidates
    __shared__ float4 res[TPB];                       // 1 KB merged results

    const int tid  = threadIdx.x;
    const int lane = tid & 63;                                  // token within block
    const int wave = __builtin_amdgcn_readfirstlane((int)(tid >> 6));
    const int e0   = wave * EPW;                                // this wave's experts
    const int swz  = lane & 15;
    const int tok0 = blockIdx.x * TPB;

    // staging decomposition: thread -> (token t0 / t0+32, f4-chunk c0)
    const int t0 = tid >> 4;            // 0..31
    const int c0 = tid & 15;
    const int soff0 = t0 * BK + ((c0 ^ (t0 & 15)) << 2);        // swizzled LDS float-offset
    const int soff1 = soff0 + 32 * BK;

    const float* xg = x + (size_t)tok0 * H_DIM;

    // opaque VGPR zero: forces W loads onto the VMEM (vmcnt) pipe, not s_load
    int vzero;
    asm volatile("v_mov_b32 %0, 0" : "=v"(vzero));
    const float4* wp = (const float4*)((const char*)W2 + vzero) + e0;

    // issue tile 0 x loads + W group 0 immediately
    float4 ra0 = *(const float4*)(xg + (size_t)t0 * H_DIM + c0 * 4);
    float4 ra1 = *(const float4*)(xg + (size_t)(t0 + 32) * H_DIM + c0 * 4);
    float4 wA[16], wB[16];
    WLOAD(wA, 0);

    // tail: emb . W[e, 2048:2112] for this wave's 8 experts (one-shot, scalar ok)
    const float* emb = se + (*sidx) * SE_DIM;
    float acc[EPW];
    #pragma unroll
    for (int i = 0; i < EPW; ++i) acc[i] = 0.0f;
    #pragma unroll
    for (int j4 = 0; j4 < SE_DIM / 4; ++j4) {
        float4 e4 = *(const float4*)(emb + 4 * j4);
        #pragma unroll
        for (int i = 0; i < EPW; ++i) {
            float4 wv = W2[(size_t)(512 + j4) * E_DIM + e0 + i];
            acc[i] = fmaf(e4.x, wv.x, acc[i]);
            acc[i] = fmaf(e4.y, wv.y, acc[i]);
            acc[i] = fmaf(e4.z, wv.z, acc[i]);
            acc[i] = fmaf(e4.w, wv.w, acc[i]);
        }
    }

    // store tile 0 (swizzled), issue tile 1 loads
    *(float4*)&xs[0][soff0] = ra0;
    *(float4*)&xs[0][soff1] = ra1;
    float4 rb0 = *(const float4*)(xg + (size_t)t0 * H_DIM + BK + c0 * 4);
    float4 rb1 = *(const float4*)(xg + (size_t)(t0 + 32) * H_DIM + BK + c0 * 4);
    float4 nr0, nr1;

    // ---- K loop: 1 barrier/tile; W double-buffered at 2-j granularity ----
    for (int kb = 0; kb < NKB; ++kb) {
        __syncthreads();                       // publish tile kb stores
        if (kb + 1 < NKB) {                    // tile kb+1 into other buffer
            *(float4*)&xs[(kb + 1) & 1][soff0] = rb0;
            *(float4*)&xs[(kb + 1) & 1][soff1] = rb1;
        }
        if (kb + 2 < NKB) {                    // issue tile kb+2 x loads
            rb0 = *(const float4*)(xg + (size_t)t0 * H_DIM + (kb + 2) * BK + c0 * 4);
            rb1 = *(const float4*)(xg + (size_t)(t0 + 32) * H_DIM + (kb + 2) * BK + c0 * 4);
        } else if (kb == NKB - 2) {            // dead slot: prefetch noise tile
            nr0 = *(const float4*)(noise + (size_t)(tok0 + t0) * E_DIM + c0 * 4);
            nr1 = *(const float4*)(noise + (size_t)(tok0 + t0 + 32) * E_DIM + c0 * 4);
        }

        const float* xb = xs[kb & 1] + lane * BK;   // this lane's token row
        #pragma unroll
        for (int jg = 0; jg < 8; ++jg) {            // 2 k4-rows per group
            const int g = kb * 8 + jg;
            float4 (&cur)[16] = (jg & 1) ? wB : wA;
            float4 (&nxt)[16] = (jg & 1) ? wA : wB;
            if (g + 1 < NGROUPS) WLOAD(nxt, g + 1); // issue next group's 16 VMEM loads
            #pragma unroll
            for (int j2 = 0; j2 < 2; ++j2) {
                const int j = jg * 2 + j2;
                float4 xv = *(const float4*)&xb[((j ^ swz) << 2)];  // 1 v_xor + ds_read_b128
                #pragma unroll
                for (int i = 0; i < EPW; ++i) {
                    float4 wv = cur[j2 * 8 + i];
                    acc[i] = fmaf(xv.x, wv.x, acc[i]);
                    acc[i] = fmaf(xv.y, wv.y, acc[i]);
                    acc[i] = fmaf(xv.z, wv.z, acc[i]);
                    acc[i] = fmaf(xv.w, wv.w, acc[i]);
                }
            }
        }
    }

    // ---- noise through the swizzled LDS path (xs[0] readers all done) ----
    *(float4*)&xs[0][soff0] = nr0;
    *(float4*)&xs[0][soff1] = nr1;
    __syncthreads();

    float4 n0 = *(const float4*)&xs[0][lane * BK + (((2 * wave)     ^ swz) << 2)];
    float4 n1 = *(const float4*)&xs[0][lane * BK + (((2 * wave + 1) ^ swz) << 2)];

    float lg[EPW];
    lg[0] = fmaf(n0.x, 0.1f, acc[0]);
    lg[1] = fmaf(n0.y, 0.1f, acc[1]);
    lg[2] = fmaf(n0.z, 0.1f, acc[2]);
    lg[3] = fmaf(n0.w, 0.1f, acc[3]);
    lg[4] = fmaf(n1.x, 0.1f, acc[4]);
    lg[5] = fmaf(n1.y, 0.1f, acc[5]);
    lg[6] = fmaf(n1.z, 0.1f, acc[6]);
    lg[7] = fmaf(n1.w, 0.1f, acc[7]);

    // per-lane top-2 of this wave's 8 experts (strict > keeps lowest index)
    float v1 = lg[0]; int i1 = 0;
    float v2 = -__builtin_inff(); int i2 = 0;
    #pragma unroll
    for (int i = 1; i < EPW; ++i) {
        if (lg[i] > v1)      { v2 = v1; i2 = i1; v1 = lg[i]; i1 = i; }
        else if (lg[i] > v2) { v2 = lg[i]; i2 = i; }
    }
    cand[wave * TPB + lane] = make_float4(v1, __int_as_float(e0 + i1),
                                          v2, __int_as_float(e0 + i2));
    __syncthreads();

    // ---- wave 0: merge 8 candidate pairs per token (ties -> lowest index) ----
    if (wave == 0) {
        float4 c = cand[lane];
        float V1 = c.x, V2 = c.z;
        int   I1 = __float_as_int(c.y), I2 = __float_as_int(c.w);
        #pragma unroll
        for (int w = 1; w < 8; ++w) {
            c = cand[w * TPB + lane];
            if (c.x > V1) {
                if (c.z > V1) { V2 = c.z; I2 = __float_as_int(c.w); }
                else          { V2 = V1;  I2 = I1; }
                V1 = c.x; I1 = __float_as_int(c.y);
            } else if (c.x > V2) {
                V2 = c.x; I2 = __float_as_int(c.y);
            }
        }
        // softmax denom cancels in top-2 renorm
        float d   = expf(V2 - V1);               // <= 1
        float inv = 1.0f / (1.0f + d);
        res[lane] = make_float4(inv, __int_as_float(I1), d * inv, __int_as_float(I2));
    }
    __syncthreads();

    // ---- coalesced composed store ----
    float4* outb = (float4*)out + (size_t)blockIdx.x * (TPB * E_DIM / 4);
    #pragma unroll
    for (int pp = 0; pp < 2; ++pp) {
        int p = tid + pp * 512;
        int t = p >> 4, cc = p & 15;
        float4 r = res[t];
        int ri1 = __float_as_int(r.y), ri2 = __float_as_int(r.w);
        int e = cc * 4;
        float4 o;
        o.x = (e + 0 == ri1) ? r.x : (e + 0 == ri2) ? r.z : 0.0f;
        o.y = (e + 1 == ri1) ? r.x : (e + 1 == ri2) ? r.z : 0.0f;
        o.z = (e + 2 == ri1) ? r.x : (e + 2 == ri2) ? r.z : 0.0f;
        o.w = (e + 3 == ri1) ? r.x : (e + 3 == ri2) ? r.z : 0.0f;
        outb[p] = o;
    }
}

extern "C" void kernel_launch(void* const* d_in, const int* in_sizes, int n_in,
                              void* d_out, int out_size, void* d_ws, size_t ws_size,
                              hipStream_t stream) {
    const float* x     = (const float*)d_in[0];
    const float* se    = (const float*)d_in[1];
    const float* W     = (const float*)d_in[2];
    const float* noise = (const float*)d_in[3];
    const int*   sidx  = (const int*)d_in[4];
    float* out = (float*)d_out;
    float4* W2 = (float4*)d_ws;      // 528 * 64 * 16 B = 540672 B

    hipLaunchKernelGGL(pack_w_kernel, dim3((E_DIM * NK4) / 256), dim3(256), 0, stream, W, W2);
    hipLaunchKernelGGL(ScaleAdaptiveRouter_kernel, dim3(NBLOCKS), dim3(512), 0, stream,
                       x, se, W2, noise, sidx, out);
}

// Round 6
// 239.239 us; speedup vs baseline: 1.7527x; 1.7527x over previous
//
#include <hip/hip_runtime.h>
#include <math.h>
#include <stdint.h>

// ScaleAdaptiveRouter on MI355X (gfx950) — Round 6: MFMA bf16x3
// T=16384, H=2048, E=64, K=2112, top-2.
// fp32 GEMM emulated as 6 bf16 MFMA terms (a0b0,a0b1,a1b0,a0b2,a1b1,a2b0);
// dropped terms ~2^-24/element -> below fp32 accumulation noise.
// lane-uniform-operand problem (R3-R5) eliminated: MFMA broadcasts in-unit.

#define H_DIM 2048
#define K_TOTAL 2112
#define E_DIM 64
#define SE_DIM 64
#define TPB 64
#define NBLOCKS 256
#define NKB 32
#define WP_TILE_BYTES 24576            // per-kb fragment chunk: 2 steps x 4 nt x 3 planes x 1KB
#define WP_TOTAL (NKB * WP_TILE_BYTES) // 786432 B

typedef float  f32x4 __attribute__((ext_vector_type(4)));
typedef short  s16x8 __attribute__((ext_vector_type(8)));

typedef uint32_t __attribute__((address_space(1))) gu32_t;
typedef uint32_t __attribute__((address_space(3))) lu32_t;
__device__ __forceinline__ void gload_lds16(const void* g, void* l) {
    __builtin_amdgcn_global_load_lds((const gu32_t*)g, (lu32_t*)l, 16, 0, 0);
}

__device__ __forceinline__ unsigned short bf16_rne(float f) {
    uint32_t u = __float_as_uint(f);
    return (unsigned short)((u + 0x7FFFu + ((u >> 16) & 1u)) >> 16);
}
__device__ __forceinline__ float bf16_f32(unsigned short h) {
    return __uint_as_float(((uint32_t)h) << 16);
}

// ---- prep: split W into 3 bf16 planes, laid out as MFMA B-fragments ----
// B-frag (16x16x32): lane l -> n = l&15, k = (l>>4)*8 + j (j=0..7).
// Wp record (s,nt,p): 64 lanes x 8 bf16 = 1 KB; record index = (s*4+nt)*3+p.
__global__ void prep_kernel(const float* __restrict__ W,
                            const float* __restrict__ se,
                            const int* __restrict__ sidx,
                            unsigned short* __restrict__ Wp,
                            float* __restrict__ tail) {
    if (blockIdx.x == 64) {
        int e = threadIdx.x;
        if (e < 64) {
            const float* emb = se + (*sidx) * SE_DIM;
            float t = 0.f;
            for (int j = 0; j < SE_DIM; ++j)
                t = fmaf(emb[j], W[(size_t)e * K_TOTAL + H_DIM + j], t);
            tail[e] = t;
        }
        return;
    }
    int item = blockIdx.x * 256 + threadIdx.x;   // (s, nt, lane): 64*4*64 = 16384
    int lane = item & 63;
    int nt   = (item >> 6) & 3;
    int s    = item >> 8;                        // K32-step 0..63
    int e     = nt * 16 + (lane & 15);
    int kbase = s * 32 + (lane >> 4) * 8;
    const float* wr = W + (size_t)e * K_TOTAL + kbase;
    unsigned short p0[8], p1[8], p2[8];
    #pragma unroll
    for (int j = 0; j < 8; ++j) {
        float v = wr[j];
        unsigned short a0 = bf16_rne(v);
        float r1 = v - bf16_f32(a0);
        unsigned short a1 = bf16_rne(r1);
        float r2 = r1 - bf16_f32(a1);
        p0[j] = a0; p1[j] = a1; p2[j] = bf16_rne(r2);
    }
    size_t rec = ((size_t)s * 4 + nt) * 3;
    unsigned short* d0 = Wp + (rec + 0) * 512 + lane * 8;  // 512 shorts per record
    unsigned short* d1 = Wp + (rec + 1) * 512 + lane * 8;
    unsigned short* d2 = Wp + (rec + 2) * 512 + lane * 8;
    #pragma unroll
    for (int j = 0; j < 8; ++j) { d0[j] = p0[j]; d1[j] = p1[j]; d2[j] = p2[j]; }
}

// split 8 floats into 3 bf16 planes packed as uint4 (one 16B granule each)
#define SPLIT8(fa, fb, U0, U1, U2) {                                          \
    float rf[8] = {fa.x, fa.y, fa.z, fa.w, fb.x, fb.y, fb.z, fb.w};           \
    unsigned short q0[8], q1[8], q2[8];                                       \
    _Pragma("unroll")                                                         \
    for (int j = 0; j < 8; ++j) {                                             \
        float v = rf[j];                                                      \
        unsigned short a0 = bf16_rne(v);                                      \
        float r1 = v - bf16_f32(a0);                                          \
        unsigned short a1 = bf16_rne(r1);                                     \
        float r2 = r1 - bf16_f32(a1);                                         \
        q0[j] = a0; q1[j] = a1; q2[j] = bf16_rne(r2);                         \
    }                                                                         \
    U0 = make_uint4(q0[0]|((uint32_t)q0[1]<<16), q0[2]|((uint32_t)q0[3]<<16), \
                    q0[4]|((uint32_t)q0[5]<<16), q0[6]|((uint32_t)q0[7]<<16));\
    U1 = make_uint4(q1[0]|((uint32_t)q1[1]<<16), q1[2]|((uint32_t)q1[3]<<16), \
                    q1[4]|((uint32_t)q1[5]<<16), q1[6]|((uint32_t)q1[7]<<16));\
    U2 = make_uint4(q2[0]|((uint32_t)q2[1]<<16), q2[2]|((uint32_t)q2[3]<<16), \
                    q2[4]|((uint32_t)q2[5]<<16), q2[6]|((uint32_t)q2[7]<<16));\
}

#define CONVSTORE(buf) {                                                      \
    uint4 g0p0, g0p1, g0p2, g1p0, g1p1, g1p2;                                 \
    SPLIT8(xr0, xr1, g0p0, g0p1, g0p2);                                       \
    SPLIT8(xr2, xr3, g1p0, g1p1, g1p2);                                       \
    *(uint4*)&xp[buf][0][woff0] = g0p0;                                       \
    *(uint4*)&xp[buf][1][woff0] = g0p1;                                       \
    *(uint4*)&xp[buf][2][woff0] = g0p2;                                       \
    *(uint4*)&xp[buf][0][woff1] = g1p0;                                       \
    *(uint4*)&xp[buf][1][woff1] = g1p1;                                       \
    *(uint4*)&xp[buf][2][woff1] = g1p2;                                       \
}

__launch_bounds__(256)
__global__ void router_kernel(const float* __restrict__ x,
                              const unsigned char* __restrict__ Wp,
                              const float* __restrict__ tail_g,
                              const float* __restrict__ noise,
                              float* __restrict__ out) {
    __shared__ __align__(16) unsigned char xp[2][3][8192];       // 48 KB x planes
    __shared__ __align__(16) unsigned char wp[2][WP_TILE_BYTES]; // 48 KB W frags
    __shared__ float4 res[TPB];
    __shared__ float  tail_lds[E_DIM];

    const int tid  = threadIdx.x;
    const int lane = tid & 63;
    const int wave = __builtin_amdgcn_readfirstlane(tid >> 6);   // m-tile 0..3
    const int tok0 = blockIdx.x * TPB;

    // x staging: thread -> (row st, k-quarter su)
    const int st = tid >> 2, su = tid & 3;
    const float* xrow = x + (size_t)(tok0 + st) * H_DIM + su * 16;
    const int woff0 = st * 128 + (((su * 2)     ^ (st & 7)) << 4);  // swizzled granules
    const int woff1 = st * 128 + (((su * 2 + 1) ^ (st & 7)) << 4);

    // A-frag read offsets: row = wave*16 + (lane&15); granule G = s2*4 + quad, pos = G^(lane&7)
    const int arow = wave * 16 + (lane & 15);
    const int aq = lane >> 4, as = lane & 7;
    const int aoff0 = arow * 128 + ((aq ^ as) << 4);
    const int aoff1 = arow * 128 + (((4 + aq) ^ as) << 4);
    const int blane = lane * 16;

    if (tid < 64) tail_lds[tid] = tail_g[tid];

    // prologue: Wp tile 0 -> wp[0]; x tile 0 -> regs
    #pragma unroll
    for (int i = 0; i < 6; ++i)
        gload_lds16(Wp + (size_t)(tid + i * 256) * 16, &wp[0][(tid + i * 256) * 16]);
    float4 xr0 = *(const float4*)(xrow + 0);
    float4 xr1 = *(const float4*)(xrow + 4);
    float4 xr2 = *(const float4*)(xrow + 8);
    float4 xr3 = *(const float4*)(xrow + 12);
    CONVSTORE(0);                           // tile 0 -> buf 0 (waits vmcnt internally)
    xr0 = *(const float4*)(xrow + 64 + 0);  // tile 1 -> regs
    xr1 = *(const float4*)(xrow + 64 + 4);
    xr2 = *(const float4*)(xrow + 64 + 8);
    xr3 = *(const float4*)(xrow + 64 + 12);

    f32x4 acc0 = {0.f, 0.f, 0.f, 0.f}, acc1 = acc0, acc2 = acc0, acc3 = acc0;

    for (int kb = 0; kb < NKB; ++kb) {
        __syncthreads();                    // publish buf kb writes (+glds vmcnt)
        const int cbuf = kb & 1, nbuf = cbuf ^ 1;
        if (kb + 1 < NKB) {
            #pragma unroll
            for (int i = 0; i < 6; ++i)
                gload_lds16(Wp + (size_t)(kb + 1) * WP_TILE_BYTES + (tid + i * 256) * 16,
                            &wp[nbuf][(tid + i * 256) * 16]);
            CONVSTORE(nbuf);                // tile kb+1 from xr
        }
        if (kb + 2 < NKB) {
            const float* p = xrow + (size_t)(kb + 2) * 64;
            xr0 = *(const float4*)(p + 0);
            xr1 = *(const float4*)(p + 4);
            xr2 = *(const float4*)(p + 8);
            xr3 = *(const float4*)(p + 12);
        } else if (kb == NKB - 1) {         // noise -> xp[0] region (16 KB, free now)
            #pragma unroll
            for (int i = 0; i < 4; ++i)
                gload_lds16(noise + (size_t)tok0 * 64 + (size_t)(tid + i * 256) * 4,
                            &xp[0][0][(tid + i * 256) * 16]);
        }

        const unsigned char* xpb = &xp[cbuf][0][0];
        const unsigned char* wb  = &wp[cbuf][0];
        #pragma unroll
        for (int s2 = 0; s2 < 2; ++s2) {
            const int aoff = s2 ? aoff1 : aoff0;
            s16x8 A0 = *(const s16x8*)&xpb[0 * 8192 + aoff];
            s16x8 A1 = *(const s16x8*)&xpb[1 * 8192 + aoff];
            s16x8 A2 = *(const s16x8*)&xpb[2 * 8192 + aoff];
            #pragma unroll
            for (int nt = 0; nt < 4; ++nt) {
                const int rb = ((s2 * 4 + nt) * 3) * 1024 + blane;
                s16x8 B0 = *(const s16x8*)&wb[rb];
                s16x8 B1 = *(const s16x8*)&wb[rb + 1024];
                s16x8 B2 = *(const s16x8*)&wb[rb + 2048];
                f32x4 a = (nt == 0) ? acc0 : (nt == 1) ? acc1 : (nt == 2) ? acc2 : acc3;
                a = __builtin_amdgcn_mfma_f32_16x16x32_bf16(A0, B0, a, 0, 0, 0);
                a = __builtin_amdgcn_mfma_f32_16x16x32_bf16(A0, B1, a, 0, 0, 0);
                a = __builtin_amdgcn_mfma_f32_16x16x32_bf16(A1, B0, a, 0, 0, 0);
                a = __builtin_amdgcn_mfma_f32_16x16x32_bf16(A0, B2, a, 0, 0, 0);
                a = __builtin_amdgcn_mfma_f32_16x16x32_bf16(A1, B1, a, 0, 0, 0);
                a = __builtin_amdgcn_mfma_f32_16x16x32_bf16(A2, B0, a, 0, 0, 0);
                if (nt == 0) acc0 = a; else if (nt == 1) acc1 = a;
                else if (nt == 2) acc2 = a; else acc3 = a;
            }
        }
    }

    __syncthreads();                        // noise visible
    const float* nz = (const float*)&xp[0][0][0];   // [64 tok][64 e]
    const int c = lane & 15;

    // C/D: col = lane&15 (expert within nt-tile), row = aq*4 + reg (token)
    #pragma unroll
    for (int r = 0; r < 4; ++r) {
        const int tloc = wave * 16 + aq * 4 + r;
        float v0 = acc0[r] + tail_lds[c]      + 0.1f * nz[tloc * 64 + c];
        float v1 = acc1[r] + tail_lds[c + 16] + 0.1f * nz[tloc * 64 + c + 16];
        float v2 = acc2[r] + tail_lds[c + 32] + 0.1f * nz[tloc * 64 + c + 32];
        float v3 = acc3[r] + tail_lds[c + 48] + 0.1f * nz[tloc * 64 + c + 48];
        // per-lane top-2 (ascending expert index, strict > keeps lowest)
        float V1 = v0; int I1 = c;
        float V2 = -__builtin_inff(); int I2 = c;
        if (v1 > V1) { V2 = V1; I2 = I1; V1 = v1; I1 = c + 16; }
        else if (v1 > V2) { V2 = v1; I2 = c + 16; }
        if (v2 > V1) { V2 = V1; I2 = I1; V1 = v2; I1 = c + 32; }
        else if (v2 > V2) { V2 = v2; I2 = c + 32; }
        if (v3 > V1) { V2 = V1; I2 = I1; V1 = v3; I1 = c + 48; }
        else if (v3 > V2) { V2 = v3; I2 = c + 48; }
        // butterfly merge across the 16 lanes of this quad
        #pragma unroll
        for (int m = 8; m; m >>= 1) {
            float o1 = __shfl_xor(V1, m, 64); int oi1 = __shfl_xor(I1, m, 64);
            float o2 = __shfl_xor(V2, m, 64); int oi2 = __shfl_xor(I2, m, 64);
            if (o1 > V1 || (o1 == V1 && oi1 < I1)) {
                float nv2; int ni2;
                if (V1 > o2 || (V1 == o2 && I1 < oi2)) { nv2 = V1; ni2 = I1; }
                else                                   { nv2 = o2; ni2 = oi2; }
                V1 = o1; I1 = oi1; V2 = nv2; I2 = ni2;
            } else {
                if (o1 > V2 || (o1 == V2 && oi1 < I2)) { V2 = o1; I2 = oi1; }
            }
        }
        if (c == r) {
            float d   = expf(V2 - V1);
            float inv = 1.0f / (1.0f + d);
            res[tloc] = make_float4(inv, __int_as_float(I1), d * inv, __int_as_float(I2));
        }
    }
    __syncthreads();

    // composed coalesced store: 64 tokens x 64 experts
    float4* outb = (float4*)out + (size_t)blockIdx.x * (TPB * E_DIM / 4);
    #pragma unroll
    for (int pp = 0; pp < 4; ++pp) {
        int p = tid + pp * 256;
        int t = p >> 4, cc = p & 15;
        float4 rr = res[t];
        int ri1 = __float_as_int(rr.y), ri2 = __float_as_int(rr.w);
        int e = cc * 4;
        float4 o;
        o.x = (e + 0 == ri1) ? rr.x : (e + 0 == ri2) ? rr.z : 0.0f;
        o.y = (e + 1 == ri1) ? rr.x : (e + 1 == ri2) ? rr.z : 0.0f;
        o.z = (e + 2 == ri1) ? rr.x : (e + 2 == ri2) ? rr.z : 0.0f;
        o.w = (e + 3 == ri1) ? rr.x : (e + 3 == ri2) ? rr.z : 0.0f;
        outb[p] = o;
    }
}

extern "C" void kernel_launch(void* const* d_in, const int* in_sizes, int n_in,
                              void* d_out, int out_size, void* d_ws, size_t ws_size,
                              hipStream_t stream) {
    const float* x     = (const float*)d_in[0];
    const float* se    = (const float*)d_in[1];
    const float* W     = (const float*)d_in[2];
    const float* noise = (const float*)d_in[3];
    const int*   sidx  = (const int*)d_in[4];
    float* out = (float*)d_out;

    unsigned short* Wp   = (unsigned short*)d_ws;                 // 786432 B
    float*          tail = (float*)((char*)d_ws + WP_TOTAL);      // 256 B

    hipLaunchKernelGGL(prep_kernel, dim3(65), dim3(256), 0, stream, W, se, sidx, Wp, tail);
    hipLaunchKernelGGL(router_kernel, dim3(NBLOCKS), dim3(256), 0, stream,
                       x, (const unsigned char*)Wp, tail, noise, out);
}

// Round 8
// 239.192 us; speedup vs baseline: 1.7530x; 1.0002x over previous
//
#include <hip/hip_runtime.h>
#include <hip/hip_bf16.h>
#include <math.h>
#include <stdint.h>

// ScaleAdaptiveRouter on MI355X (gfx950) — Round 8: barrier-free MFMA bf16x3
// (R7 with the __builtin_bit_cast(uint32_t, __hip_bfloat162) compile error
//  fixed via __builtin_memcpy bit-copy; no other changes.)
//
// R6 post-mortem: LDS double-buffer structure ran at 1 block/CU, 1 wave/SIMD
// (LDS 97.5 KB) -> per-tile barrier + 24KB W drain fully exposed (MfmaUtil
// 10%, VALUBusy 14%). R7/R8 removes LDS from the dataflow:
//   * W pre-packed in fragment order (prep kernel, R6-verified layout) ->
//     per-lane B-frag = coalesced 16B global load, register-pipelined.
//   * x loaded per-wave directly in A-fragment shape, split to 3 bf16
//     planes in-register via packed v_cvt_pk_bf16_f32.
//   * No K-loop barriers; epilogue uses 1KB LDS only.
// 6-term bf16x3 product (a0b0,a0b1,a1b0,a0b2,a1b1,a2b0): error ~2^-24/elt,
// below fp32 accumulation noise (R6 passed at the same absmax as fp32 rounds).

#define H_DIM 2048
#define K_TOTAL 2112
#define E_DIM 64
#define SE_DIM 64
#define TPB 64
#define NBLOCKS 256
#define NSTEP 64                        // K32 steps over H
#define WP_TOTAL (NSTEP * 12 * 1024)    // 786432 B

typedef float  f32x4 __attribute__((ext_vector_type(4)));
typedef short  s16x8 __attribute__((ext_vector_type(8)));
typedef unsigned int u32x4 __attribute__((ext_vector_type(4)));

__device__ __forceinline__ unsigned short bf16_rne(float f) {
    uint32_t u = __float_as_uint(f);
    return (unsigned short)((u + 0x7FFFu + ((u >> 16) & 1u)) >> 16);
}
__device__ __forceinline__ float bf16_f32(unsigned short h) {
    return __uint_as_float(((uint32_t)h) << 16);
}
__device__ __forceinline__ uint32_t bits_of_bf2(__hip_bfloat162 h) {
    uint32_t u; __builtin_memcpy(&u, &h, 4); return u;   // byte copy, no-op in ISA
}

// ---- prep: split W into 3 bf16 planes laid out as MFMA B-fragments ----
// B-frag (16x16x32): lane l -> n = l&15, k = (l>>4)*8 + j. Record (s,nt,p):
// 64 lanes x 8 bf16 = 1 KB; record index = s*12 + nt*3 + p.  [R6-verified]
__global__ void prep_kernel(const float* __restrict__ W,
                            const float* __restrict__ se,
                            const int* __restrict__ sidx,
                            unsigned short* __restrict__ Wp,
                            float* __restrict__ tail) {
    if (blockIdx.x == 64) {
        int e = threadIdx.x;
        if (e < 64) {
            const float* emb = se + (*sidx) * SE_DIM;
            float t = 0.f;
            for (int j = 0; j < SE_DIM; ++j)
                t = fmaf(emb[j], W[(size_t)e * K_TOTAL + H_DIM + j], t);
            tail[e] = t;
        }
        return;
    }
    int item = blockIdx.x * 256 + threadIdx.x;   // (s, nt, lane)
    int lane = item & 63;
    int nt   = (item >> 6) & 3;
    int s    = item >> 8;
    int e     = nt * 16 + (lane & 15);
    int kbase = s * 32 + (lane >> 4) * 8;
    const float* wr = W + (size_t)e * K_TOTAL + kbase;
    unsigned short p0[8], p1[8], p2[8];
    #pragma unroll
    for (int j = 0; j < 8; ++j) {
        float v = wr[j];
        unsigned short a0 = bf16_rne(v);
        float r1 = v - bf16_f32(a0);
        unsigned short a1 = bf16_rne(r1);
        float r2 = r1 - bf16_f32(a1);
        p0[j] = a0; p1[j] = a1; p2[j] = bf16_rne(r2);
    }
    size_t rec = (size_t)s * 12 + nt * 3;
    unsigned short* d0 = Wp + (rec + 0) * 512 + lane * 8;
    unsigned short* d1 = Wp + (rec + 1) * 512 + lane * 8;
    unsigned short* d2 = Wp + (rec + 2) * 512 + lane * 8;
    #pragma unroll
    for (int j = 0; j < 8; ++j) { d0[j] = p0[j]; d1[j] = p1[j]; d2[j] = p2[j]; }
}

// split 8 consecutive-k floats into 3 bf16 A-fragment planes (packed pairs)
__device__ __forceinline__ void split3(const float4 fa, const float4 fb,
                                       s16x8& P0, s16x8& P1, s16x8& P2) {
    float f[8] = {fa.x, fa.y, fa.z, fa.w, fb.x, fb.y, fb.z, fb.w};
    uint32_t d0[4], d1[4], d2[4];
    #pragma unroll
    for (int p = 0; p < 4; ++p) {
        float v0 = f[2 * p], v1 = f[2 * p + 1];
        uint32_t u0 = bits_of_bf2(__float22bfloat162_rn(make_float2(v0, v1)));
        float r0 = v0 - __uint_as_float(u0 << 16);
        float r1 = v1 - __uint_as_float(u0 & 0xffff0000u);
        uint32_t u1 = bits_of_bf2(__float22bfloat162_rn(make_float2(r0, r1)));
        float s0 = r0 - __uint_as_float(u1 << 16);
        float s1 = r1 - __uint_as_float(u1 & 0xffff0000u);
        uint32_t u2 = bits_of_bf2(__float22bfloat162_rn(make_float2(s0, s1)));
        d0[p] = u0; d1[p] = u1; d2[p] = u2;
    }
    u32x4 q0 = {d0[0], d0[1], d0[2], d0[3]};
    u32x4 q1 = {d1[0], d1[1], d1[2], d1[3]};
    u32x4 q2 = {d2[0], d2[1], d2[2], d2[3]};
    __builtin_memcpy(&P0, &q0, 16);
    __builtin_memcpy(&P1, &q1, 16);
    __builtin_memcpy(&P2, &q2, 16);
}

__launch_bounds__(256, 1)
__global__ void router_kernel(const float* __restrict__ x,
                              const uint4* __restrict__ wp4,
                              const float* __restrict__ tail_g,
                              const float* __restrict__ noise,
                              float* __restrict__ out) {
    __shared__ float4 res[TPB];         // only LDS in the kernel (1 KB)

    const int tid  = threadIdx.x;
    const int lane = tid & 63;
    const int wave = __builtin_amdgcn_readfirstlane(tid >> 6);   // m-tile 0..3
    const int tok0 = blockIdx.x * TPB;
    const int row  = lane & 15;                                  // token within m-tile
    const int quad = lane >> 4;                                  // k-quad
    const int c    = row;                                        // expert col within nt

    // A source: this lane's token row, k = s*32 + quad*8 + (0..7)
    const float* aptr = x + (size_t)(tok0 + wave * 16 + row) * H_DIM + quad * 8;

    f32x4 acc[4];
    #pragma unroll
    for (int nt = 0; nt < 4; ++nt) acc[nt] = (f32x4){0.f, 0.f, 0.f, 0.f};

    // ---- prologue: step-0 operands ----
    float4 arA = *(const float4*)(aptr);
    float4 arB = *(const float4*)(aptr + 4);
    uint4 bcur[12];
    #pragma unroll
    for (int q = 0; q < 12; ++q) bcur[q] = wp4[(size_t)q * 64 + lane];

    // ---- barrier-free K loop: prefetch s+1, compute s ----
    #pragma unroll 2
    for (int s = 0; s < NSTEP; ++s) {
        float4 nrA, nrB;
        uint4 bnxt[12];
        if (s + 1 < NSTEP) {
            const float* ap = aptr + (size_t)(s + 1) * 32;
            nrA = *(const float4*)(ap);
            nrB = *(const float4*)(ap + 4);
            #pragma unroll
            for (int q = 0; q < 12; ++q)
                bnxt[q] = wp4[((size_t)(s + 1) * 12 + q) * 64 + lane];
        }
        s16x8 A0, A1, A2;
        split3(arA, arB, A0, A1, A2);
        #pragma unroll
        for (int nt = 0; nt < 4; ++nt) {
            s16x8 B0, B1, B2;
            __builtin_memcpy(&B0, &bcur[nt * 3 + 0], 16);
            __builtin_memcpy(&B1, &bcur[nt * 3 + 1], 16);
            __builtin_memcpy(&B2, &bcur[nt * 3 + 2], 16);
            f32x4 a = acc[nt];
            a = __builtin_amdgcn_mfma_f32_16x16x32_bf16(A0, B0, a, 0, 0, 0);
            a = __builtin_amdgcn_mfma_f32_16x16x32_bf16(A0, B1, a, 0, 0, 0);
            a = __builtin_amdgcn_mfma_f32_16x16x32_bf16(A1, B0, a, 0, 0, 0);
            a = __builtin_amdgcn_mfma_f32_16x16x32_bf16(A0, B2, a, 0, 0, 0);
            a = __builtin_amdgcn_mfma_f32_16x16x32_bf16(A1, B1, a, 0, 0, 0);
            a = __builtin_amdgcn_mfma_f32_16x16x32_bf16(A2, B0, a, 0, 0, 0);
            acc[nt] = a;
        }
        arA = nrA; arB = nrB;
        #pragma unroll
        for (int q = 0; q < 12; ++q) bcur[q] = bnxt[q];
    }

    // ---- epilogue: tail + noise, top-2, renorm (R6-verified) ----
    // C/D: col = lane&15 (expert within nt), row = quad*4 + reg (token in m-tile)
    float tl0 = tail_g[c],      tl1 = tail_g[c + 16];
    float tl2 = tail_g[c + 32], tl3 = tail_g[c + 48];
    #pragma unroll
    for (int r = 0; r < 4; ++r) {
        const int tloc = wave * 16 + quad * 4 + r;
        const float* nz = noise + (size_t)(tok0 + tloc) * E_DIM;
        float v0 = acc[0][r] + tl0 + 0.1f * nz[c];
        float v1 = acc[1][r] + tl1 + 0.1f * nz[c + 16];
        float v2 = acc[2][r] + tl2 + 0.1f * nz[c + 32];
        float v3 = acc[3][r] + tl3 + 0.1f * nz[c + 48];
        // per-lane top-2 over the 4 nt-slices (ascending index, strict >)
        float V1 = v0; int I1 = c;
        float V2 = -__builtin_inff(); int I2 = c;
        if (v1 > V1) { V2 = V1; I2 = I1; V1 = v1; I1 = c + 16; }
        else if (v1 > V2) { V2 = v1; I2 = c + 16; }
        if (v2 > V1) { V2 = V1; I2 = I1; V1 = v2; I1 = c + 32; }
        else if (v2 > V2) { V2 = v2; I2 = c + 32; }
        if (v3 > V1) { V2 = V1; I2 = I1; V1 = v3; I1 = c + 48; }
        else if (v3 > V2) { V2 = v3; I2 = c + 48; }
        // butterfly merge across the 16 lanes of this quad
        #pragma unroll
        for (int m = 8; m; m >>= 1) {
            float o1 = __shfl_xor(V1, m, 64); int oi1 = __shfl_xor(I1, m, 64);
            float o2 = __shfl_xor(V2, m, 64); int oi2 = __shfl_xor(I2, m, 64);
            if (o1 > V1 || (o1 == V1 && oi1 < I1)) {
                float nv2; int ni2;
                if (V1 > o2 || (V1 == o2 && I1 < oi2)) { nv2 = V1; ni2 = I1; }
                else                                   { nv2 = o2; ni2 = oi2; }
                V1 = o1; I1 = oi1; V2 = nv2; I2 = ni2;
            } else {
                if (o1 > V2 || (o1 == V2 && oi1 < I2)) { V2 = o1; I2 = oi1; }
            }
        }
        if (c == r) {
            float d   = expf(V2 - V1);          // softmax denom cancels in renorm
            float inv = 1.0f / (1.0f + d);
            res[tloc] = make_float4(inv, __int_as_float(I1), d * inv, __int_as_float(I2));
        }
    }
    __syncthreads();

    // ---- composed coalesced store: 64 tokens x 64 experts ----
    float4* outb = (float4*)out + (size_t)blockIdx.x * (TPB * E_DIM / 4);
    #pragma unroll
    for (int pp = 0; pp < 4; ++pp) {
        int p = tid + pp * 256;
        int t = p >> 4, cc = p & 15;
        float4 rr = res[t];
        int ri1 = __float_as_int(rr.y), ri2 = __float_as_int(rr.w);
        int e = cc * 4;
        float4 o;
        o.x = (e + 0 == ri1) ? rr.x : (e + 0 == ri2) ? rr.z : 0.0f;
        o.y = (e + 1 == ri1) ? rr.x : (e + 1 == ri2) ? rr.z : 0.0f;
        o.z = (e + 2 == ri1) ? rr.x : (e + 2 == ri2) ? rr.z : 0.0f;
        o.w = (e + 3 == ri1) ? rr.x : (e + 3 == ri2) ? rr.z : 0.0f;
        outb[p] = o;
    }
}

extern "C" void kernel_launch(void* const* d_in, const int* in_sizes, int n_in,
                              void* d_out, int out_size, void* d_ws, size_t ws_size,
                              hipStream_t stream) {
    const float* x     = (const float*)d_in[0];
    const float* se    = (const float*)d_in[1];
    const float* W     = (const float*)d_in[2];
    const float* noise = (const float*)d_in[3];
    const int*   sidx  = (const int*)d_in[4];
    float* out = (float*)d_out;

    unsigned short* Wp   = (unsigned short*)d_ws;                 // 786432 B
    float*          tail = (float*)((char*)d_ws + WP_TOTAL);      // 256 B

    hipLaunchKernelGGL(prep_kernel, dim3(65), dim3(256), 0, stream, W, se, sidx, Wp, tail);
    hipLaunchKernelGGL(router_kernel, dim3(NBLOCKS), dim3(256), 0, stream,
                       x, (const uint4*)Wp, tail, noise, out);
}